// Round 1
// baseline (187.121 us; speedup 1.0000x reference)
//
#include <hip/hip_runtime.h>
#include <stdint.h>

typedef __bf16 bf16;
typedef __attribute__((ext_vector_type(8))) __bf16 bf16x8;
typedef __attribute__((ext_vector_type(4))) __bf16 bf16x4;
typedef __attribute__((ext_vector_type(4))) float  f32x4;

#define ATT_SCALE 0.125f   // 1/sqrt(64)

// ---------------------------------------------------------------------------
// async 16B global -> LDS (wave-uniform LDS base + lane*16, per-lane gaddr)
// ---------------------------------------------------------------------------
__device__ __forceinline__ void async16(void* lds, const void* g) {
  __builtin_amdgcn_global_load_lds(
      (__attribute__((address_space(1))) void*)(void*)g,
      (__attribute__((address_space(3))) void*)lds,
      16, 0, 0);
}

// ---------------------------------------------------------------------------
// fp32 -> bf16 convert, 8 elems/thread
// ---------------------------------------------------------------------------
__global__ void convert_x_kernel(const float* __restrict__ x, bf16* __restrict__ y) {
  size_t i = ((size_t)blockIdx.x * 256 + threadIdx.x) * 8;
  float4 a = *(const float4*)(x + i);
  float4 b = *(const float4*)(x + i + 4);
  bf16x8 o;
  o[0] = (bf16)a.x; o[1] = (bf16)a.y; o[2] = (bf16)a.z; o[3] = (bf16)a.w;
  o[4] = (bf16)b.x; o[5] = (bf16)b.y; o[6] = (bf16)b.z; o[7] = (bf16)b.w;
  *(bf16x8*)(y + i) = o;
}

// ---------------------------------------------------------------------------
// W [768 x 2304] fp32  ->  Wt [2304 x 768] bf16  (LDS tiled transpose)
// ---------------------------------------------------------------------------
__global__ void transpose_w_kernel(const float* __restrict__ W, bf16* __restrict__ Wt) {
  __shared__ float tile[32][33];
  int tx = threadIdx.x, ty = threadIdx.y;
  int n0 = blockIdx.x * 32, k0 = blockIdx.y * 32;
#pragma unroll
  for (int r = 0; r < 4; ++r)
    tile[ty + r * 8][tx] = W[(size_t)(k0 + ty + r * 8) * 2304 + n0 + tx];
  __syncthreads();
#pragma unroll
  for (int r = 0; r < 4; ++r)
    Wt[(size_t)(n0 + ty + r * 8) * 768 + k0 + tx] = (bf16)tile[tx][ty + r * 8];
}

// ---------------------------------------------------------------------------
// QKV GEMM: C[8192 x 2304] = A[8192 x 768] * W + bias
//   A row-major bf16, Wt = W^T row-major bf16 (both k-contiguous).
//   Tile 128x128, BK=32, 4 waves each 64x64 (4x4 of 16x16x32 MFMA).
//   LDS layout per operand: 4 k-blocks of (128 rows x 16B), 16B pad between
//   k-blocks (stride 2064B) so frag ds_read_b128 is <=4-way conflicted.
//   Epilogue: +bias, ->bf16, scatter into Q[bh][t][64], K[bh][t][64],
//   V^T[bh][64][t] (V packed 4 consecutive t per 8B store).
// ---------------------------------------------------------------------------
__global__ void qkv_gemm_kernel(const bf16* __restrict__ A, const bf16* __restrict__ Bw,
                                const float* __restrict__ bias,
                                bf16* __restrict__ Qo, bf16* __restrict__ Ko,
                                bf16* __restrict__ Vo) {
  __shared__ __align__(16) char lds[16512];
  char* Al = lds;
  char* Bl = lds + 8256;

  const int tid  = threadIdx.x;
  const int wave = tid >> 6, lane = tid & 63;
  const int quad = lane >> 4, mn = lane & 15;
  const int wr = wave >> 1, wc = wave & 1;
  const int m0 = blockIdx.y * 128;
  const int n0 = blockIdx.x * 128;

  f32x4 acc[4][4] = {};

  const int kb = wave;  // each wave DMAs one k-block (8 k) of both tiles
  for (int kt = 0; kt < 768; kt += 32) {
#pragma unroll
    for (int half = 0; half < 2; ++half) {
      const bf16* ga = A  + (size_t)(m0 + half * 64 + lane) * 768 + kt + kb * 8;
      async16(Al + kb * 2064 + half * 1024, ga);
      const bf16* gb = Bw + (size_t)(n0 + half * 64 + lane) * 768 + kt + kb * 8;
      async16(Bl + kb * 2064 + half * 1024, gb);
    }
    __syncthreads();

    bf16x8 af[4], bfr[4];
#pragma unroll
    for (int i = 0; i < 4; ++i) {
      af[i]  = *(const bf16x8*)(Al + quad * 2064 + (wr * 64 + i * 16 + mn) * 16);
      bfr[i] = *(const bf16x8*)(Bl + quad * 2064 + (wc * 64 + i * 16 + mn) * 16);
    }
#pragma unroll
    for (int i = 0; i < 4; ++i)
#pragma unroll
      for (int j = 0; j < 4; ++j)
        acc[i][j] = __builtin_amdgcn_mfma_f32_16x16x32_bf16(af[i], bfr[j], acc[i][j], 0, 0, 0);
    __syncthreads();
  }

  // epilogue
  const int ng    = n0 + wc * 64;       // wave's global col base (mult of 64)
  const int third = ng / 768;           // 0=Q 1=K 2=V (block stays in one third)
  const int nmod  = ng % 768;
#pragma unroll
  for (int ct = 0; ct < 4; ++ct) {
    int n = nmod + ct * 16 + mn;        // 0..767 within third
    int h = n >> 6, d = n & 63;
    float bv = bias[third * 768 + n];
#pragma unroll
    for (int rt = 0; rt < 4; ++rt) {
      int m  = m0 + wr * 64 + rt * 16 + quad * 4;   // first of 4 consecutive rows
      int b  = m >> 10, t0 = m & 1023;
      size_t bh = (size_t)b * 12 + h;
      if (third == 2) {
        bf16x4 p;
#pragma unroll
        for (int r = 0; r < 4; ++r) p[r] = (bf16)(acc[rt][ct][r] + bv);
        *(bf16x4*)(Vo + (bh * 64 + d) * 1024 + t0) = p;   // V^T: 4 consecutive t
      } else {
        bf16* dst = (third == 0 ? Qo : Ko) + (bh * 1024 + t0) * 64 + d;
#pragma unroll
        for (int r = 0; r < 4; ++r) dst[(size_t)r * 64] = (bf16)(acc[rt][ct][r] + bv);
      }
    }
  }
}

// ---------------------------------------------------------------------------
// Attention: per block = one (bh, 64-row Q tile). 4 waves, 16 q-rows each.
//   Loop kv tiles j=0..qt (causal skip). K tile [64t x 64d] and V^T tile
//   [64d x 64t] staged in LDS with pitch 72 elems (144B, 16B aligned).
//   S = relu(mask(Q K^T * scale)) -> bf16 via LDS round-trip -> Y += S V.
// ---------------------------------------------------------------------------
__global__ void attn_kernel(const bf16* __restrict__ Q, const bf16* __restrict__ K,
                            const bf16* __restrict__ Vt, float* __restrict__ out) {
  __shared__ __align__(16) char lds[27648];
  char* ldsK = lds;              // 64 x 72 bf16
  char* ldsV = lds + 9216;       // 64 x 72 bf16 (rows = d, cols = t_local)
  char* ldsS = lds + 18432;      // 64 x 72 bf16 (rows = q_local, cols = kk_local)

  const int tid  = threadIdx.x;
  const int wave = tid >> 6, lane = tid & 63;
  const int quad = lane >> 4, mn = lane & 15;
  const int bh = blockIdx.x;
  const int qt = (int)gridDim.y - 1 - (int)blockIdx.y;   // heavy tiles first
  const int q0 = qt * 64;

  // Q fragments (A operand) straight from global: row = q0+wave*16+mn
  const bf16* Qrow = Q + ((size_t)bh * 1024 + q0 + wave * 16 + mn) * 64;
  bf16x8 qf0 = *(const bf16x8*)(Qrow + quad * 8);
  bf16x8 qf1 = *(const bf16x8*)(Qrow + 32 + quad * 8);

  f32x4 yacc[4] = {};

  const int trow = tid >> 3;     // 0..31 (staging row)
  const int tcol = tid & 7;      // 0..7  (staging 16B chunk within row)
  const bf16* Kg0 = K  + (size_t)bh * 1024 * 64;
  const bf16* Vg0 = Vt + (size_t)bh * 64 * 1024;

  for (int j = 0; j <= qt; ++j) {
    __syncthreads();   // previous iter's LDS reads complete
    {
      const bf16* Kg = Kg0 + (size_t)j * 64 * 64;
      const bf16* Vg = Vg0 + j * 64;
      bf16x8 r0 = *(const bf16x8*)(Kg + trow * 64 + tcol * 8);
      bf16x8 r1 = *(const bf16x8*)(Kg + (trow + 32) * 64 + tcol * 8);
      bf16x8 r2 = *(const bf16x8*)(Vg + (size_t)trow * 1024 + tcol * 8);
      bf16x8 r3 = *(const bf16x8*)(Vg + (size_t)(trow + 32) * 1024 + tcol * 8);
      *(bf16x8*)(ldsK + trow * 144 + tcol * 16) = r0;
      *(bf16x8*)(ldsK + (trow + 32) * 144 + tcol * 16) = r1;
      *(bf16x8*)(ldsV + trow * 144 + tcol * 16) = r2;
      *(bf16x8*)(ldsV + (trow + 32) * 144 + tcol * 16) = r3;
    }
    __syncthreads();

    // S tile: wave's 16 q-rows x 64 kk
    f32x4 s[4];
#pragma unroll
    for (int ct = 0; ct < 4; ++ct) {
      bf16x8 kf0 = *(const bf16x8*)(ldsK + (ct * 16 + mn) * 144 + quad * 16);
      bf16x8 kf1 = *(const bf16x8*)(ldsK + (ct * 16 + mn) * 144 + 64 + quad * 16);
      f32x4 a = {};
      a = __builtin_amdgcn_mfma_f32_16x16x32_bf16(qf0, kf0, a, 0, 0, 0);
      a = __builtin_amdgcn_mfma_f32_16x16x32_bf16(qf1, kf1, a, 0, 0, 0);
      s[ct] = a;
    }

    // scale, causal mask (diag tile only), relu, -> bf16 in LDS
    const int qrow = q0 + wave * 16 + quad * 4;
    const bool diag = (j == qt);
#pragma unroll
    for (int ct = 0; ct < 4; ++ct) {
      int kk = j * 64 + ct * 16 + mn;
#pragma unroll
      for (int r = 0; r < 4; ++r) {
        float v = s[ct][r] * ATT_SCALE;
        v = v > 0.f ? v : 0.f;
        if (diag && kk > qrow + r) v = 0.f;
        ((bf16*)ldsS)[(wave * 16 + quad * 4 + r) * 72 + ct * 16 + mn] = (bf16)v;
      }
    }
    __syncthreads();

    // Y += S * V  (A = S from LDS in A-layout, B = V via Vt rows)
#pragma unroll
    for (int kb = 0; kb < 2; ++kb) {
      bf16x8 sf = *(const bf16x8*)(ldsS + (wave * 16 + mn) * 144 + kb * 64 + quad * 16);
#pragma unroll
      for (int ct = 0; ct < 4; ++ct) {
        bf16x8 vf = *(const bf16x8*)(ldsV + (ct * 16 + mn) * 144 + kb * 64 + quad * 16);
        yacc[ct] = __builtin_amdgcn_mfma_f32_16x16x32_bf16(sf, vf, yacc[ct], 0, 0, 0);
      }
    }
  }

  // write out: out[b][t][h*64+d]
  const int b = bh / 12, h = bh % 12;
  float* ob = out + ((size_t)b * 1024 + q0 + wave * 16 + quad * 4) * 768 + h * 64;
#pragma unroll
  for (int ct = 0; ct < 4; ++ct)
#pragma unroll
    for (int r = 0; r < 4; ++r)
      ob[(size_t)r * 768 + ct * 16 + mn] = yacc[ct][r];
}

// ---------------------------------------------------------------------------
extern "C" void kernel_launch(void* const* d_in, const int* in_sizes, int n_in,
                              void* d_out, int out_size, void* d_ws, size_t ws_size,
                              hipStream_t stream) {
  const float* x    = (const float*)d_in[0];   // [8,1024,768]
  const float* W    = (const float*)d_in[1];   // [768,2304]
  const float* bias = (const float*)d_in[2];   // [2304]
  float* out = (float*)d_out;                  // [8,1024,768]

  char* ws = (char*)d_ws;
  bf16* xb = (bf16*)(ws);                      // 8192*768        = 12,582,912 B
  bf16* Wt = (bf16*)(ws + 12582912);           // 2304*768        =  3,538,944 B
  bf16* Qb = (bf16*)(ws + 16121856);           // 96*1024*64      = 12,582,912 B
  bf16* Kb = (bf16*)(ws + 28704768);           // 96*1024*64      = 12,582,912 B
  bf16* Vb = (bf16*)(ws + 41287680);           // 96*64*1024 (V^T)= 12,582,912 B

  convert_x_kernel<<<3072, 256, 0, stream>>>(x, xb);
  transpose_w_kernel<<<dim3(72, 24), dim3(32, 8), 0, stream>>>(W, Wt);
  qkv_gemm_kernel<<<dim3(18, 64), 256, 0, stream>>>(xb, Wt, bias, Qb, Kb, Vb);
  attn_kernel<<<dim3(96, 16), 256, 0, stream>>>(Qb, Kb, Vb, out);
}